// Round 1
// baseline (294.877 us; speedup 1.0000x reference)
//
#include <hip/hip_runtime.h>

#define NN 50000
#define EE 1600000
#define INF 128
#define OUTF 64
#define NH 2
#define ALPHA 0.2f

// ws layout (floats): si [0,1e5) sj [1e5,2e5) c [2e5,3e5) Z [3e5,3e5+2)

__global__ __launch_bounds__(128)
void gat_node(const float* __restrict__ x, const float* __restrict__ W,
              const float* __restrict__ a, float* __restrict__ out,
              float* __restrict__ si, float* __restrict__ sj,
              float* __restrict__ cacc, float* __restrict__ Z)
{
    __shared__ float Wl[INF * OUTF];        // 32 KB: W[head][i][o] -> Wl[i*64+o]
    const int h = blockIdx.x & 1;
    const int tile = blockIdx.x >> 1;
    const int n0 = tile * 128;

    {
        const float4* src = (const float4*)(W + h * (INF * OUTF));
        float4* dst = (float4*)Wl;
        #pragma unroll 4
        for (int k = threadIdx.x; k < (INF * OUTF) / 4; k += 128) dst[k] = src[k];
    }
    if (blockIdx.x == 0 && threadIdx.x < 2) Z[threadIdx.x] = 0.0f;

    const int tx = threadIdx.x & 7;   // output octet: outs tx*8..tx*8+7 (within head)
    const int ty = threadIdx.x >> 3;  // node group: nodes n0+ty*8 .. +7

    float ai[8], aj[8];
    #pragma unroll
    for (int c = 0; c < 8; ++c) {
        ai[c] = a[h * 2 * OUTF + tx * 8 + c];
        aj[c] = a[h * 2 * OUTF + OUTF + tx * 8 + c];
    }

    const float4* xp[8];
    #pragma unroll
    for (int k = 0; k < 8; ++k) {
        int n = n0 + ty * 8 + k;
        if (n >= NN) n = NN - 1;           // clamp: loads valid, stores guarded
        xp[k] = (const float4*)(x + (size_t)n * INF);
    }

    float acc[8][8];
    #pragma unroll
    for (int k = 0; k < 8; ++k)
        #pragma unroll
        for (int c = 0; c < 8; ++c) acc[k][c] = 0.0f;

    __syncthreads();

    // software-pipelined x fetch (global, 8-lane broadcast per address)
    float4 xv[8];
    #pragma unroll
    for (int k = 0; k < 8; ++k) xv[k] = xp[k][0];

    for (int i4 = 0; i4 < INF / 4; ++i4) {
        const int nxt = (i4 + 1 < INF / 4) ? i4 + 1 : i4;
        float4 xn[8];
        #pragma unroll
        for (int k = 0; k < 8; ++k) xn[k] = xp[k][nxt];

        float4 wa[4], wb[4];
        #pragma unroll
        for (int r = 0; r < 4; ++r) {
            const float* wrow = &Wl[(i4 * 4 + r) * OUTF + tx * 8];
            wa[r] = *(const float4*)(wrow);
            wb[r] = *(const float4*)(wrow + 4);
        }
        #pragma unroll
        for (int k = 0; k < 8; ++k) {
            const float* xk = (const float*)&xv[k];
            #pragma unroll
            for (int r = 0; r < 4; ++r) {
                const float xs = xk[r];
                acc[k][0] = fmaf(xs, wa[r].x, acc[k][0]);
                acc[k][1] = fmaf(xs, wa[r].y, acc[k][1]);
                acc[k][2] = fmaf(xs, wa[r].z, acc[k][2]);
                acc[k][3] = fmaf(xs, wa[r].w, acc[k][3]);
                acc[k][4] = fmaf(xs, wb[r].x, acc[k][4]);
                acc[k][5] = fmaf(xs, wb[r].y, acc[k][5]);
                acc[k][6] = fmaf(xs, wb[r].z, acc[k][6]);
                acc[k][7] = fmaf(xs, wb[r].w, acc[k][7]);
            }
        }
        #pragma unroll
        for (int k = 0; k < 8; ++k) xv[k] = xn[k];
    }

    // epilogue: attention scores s_i/s_j (8-lane shuffle reduce), zero c, write Wh
    #pragma unroll
    for (int k = 0; k < 8; ++k) {
        float pi = 0.0f, pj = 0.0f;
        #pragma unroll
        for (int c = 0; c < 8; ++c) {
            pi = fmaf(acc[k][c], ai[c], pi);
            pj = fmaf(acc[k][c], aj[c], pj);
        }
        #pragma unroll
        for (int m = 1; m < 8; m <<= 1) {
            pi += __shfl_xor(pi, m, 64);
            pj += __shfl_xor(pj, m, 64);
        }
        const int n = n0 + ty * 8 + k;
        if (n < NN) {
            if (tx == 0) {
                si[2 * n + h] = pi;
                sj[2 * n + h] = pj;
                cacc[2 * n + h] = 0.0f;
            }
            float4* o4 = (float4*)(out + (size_t)n * (NH * OUTF) + h * OUTF + tx * 8);
            o4[0] = make_float4(acc[k][0], acc[k][1], acc[k][2], acc[k][3]);
            o4[1] = make_float4(acc[k][4], acc[k][5], acc[k][6], acc[k][7]);
        }
    }
}

__global__ __launch_bounds__(256)
void gat_edge(const int* __restrict__ ei, const float* __restrict__ si,
              const float* __restrict__ sj, float* __restrict__ cacc,
              float* __restrict__ Z)
{
    __shared__ float red0[4], red1[4];
    const int t = blockIdx.x * 256 + threadIdx.x;
    float z0 = 0.0f, z1 = 0.0f;
    const int e0 = t * 4;
    if (e0 < EE) {
        const int4 s4 = *(const int4*)&ei[e0];
        const int4 d4 = *(const int4*)&ei[EE + e0];
        const int ss[4] = {s4.x, s4.y, s4.z, s4.w};
        const int dd[4] = {d4.x, d4.y, d4.z, d4.w};
        #pragma unroll
        for (int k = 0; k < 4; ++k) {
            const float2 vi = *(const float2*)&si[2 * ss[k]];
            const float2 vj = *(const float2*)&sj[2 * dd[k]];
            float a0 = vi.x + vj.x; a0 = a0 > 0.0f ? a0 : ALPHA * a0;
            float a1 = vi.y + vj.y; a1 = a1 > 0.0f ? a1 : ALPHA * a1;
            const float w0 = expf(a0);
            const float w1 = expf(a1);
            atomicAdd(&cacc[2 * dd[k]], w0);
            atomicAdd(&cacc[2 * dd[k] + 1], w1);
            z0 += w0; z1 += w1;
        }
    }
    #pragma unroll
    for (int m = 1; m < 64; m <<= 1) {
        z0 += __shfl_xor(z0, m, 64);
        z1 += __shfl_xor(z1, m, 64);
    }
    const int wave = threadIdx.x >> 6;
    if ((threadIdx.x & 63) == 0) { red0[wave] = z0; red1[wave] = z1; }
    __syncthreads();
    if (threadIdx.x == 0) {
        atomicAdd(&Z[0], red0[0] + red0[1] + red0[2] + red0[3]);
        atomicAdd(&Z[1], red1[0] + red1[1] + red1[2] + red1[3]);
    }
}

__global__ __launch_bounds__(256)
void gat_final(float* __restrict__ out, const float* __restrict__ cacc,
               const float* __restrict__ Z)
{
    const int total4 = NN * NH * OUTF / 4;   // 1,600,000
    const int idx = blockIdx.x * 256 + threadIdx.x;
    if (idx >= total4) return;
    const int base = idx << 2;
    const int n = base >> 7;
    const int h = (base >> 6) & 1;
    const float scale = cacc[2 * n + h] / Z[h];
    float4* p = (float4*)out + idx;
    float4 v = *p;
    v.x *= scale; v.y *= scale; v.z *= scale; v.w *= scale;
    *p = v;
}

extern "C" void kernel_launch(void* const* d_in, const int* in_sizes, int n_in,
                              void* d_out, int out_size, void* d_ws, size_t ws_size,
                              hipStream_t stream)
{
    const float* x = (const float*)d_in[0];
    const float* W = (const float*)d_in[1];
    const float* a = (const float*)d_in[2];
    const int* ei = (const int*)d_in[3];
    float* out = (float*)d_out;
    float* ws = (float*)d_ws;

    float* si = ws;
    float* sj = ws + 100000;
    float* cacc = ws + 200000;
    float* Z = ws + 300000;

    const int tiles = (NN + 127) / 128;                    // 391
    gat_node<<<dim3(tiles * NH), dim3(128), 0, stream>>>(x, W, a, out, si, sj, cacc, Z);

    const int eblocks = (EE / 4 + 255) / 256;              // 1563
    gat_edge<<<dim3(eblocks), dim3(256), 0, stream>>>(ei, si, sj, cacc, Z);

    const int fblocks = (NN * NH * OUTF / 4 + 255) / 256;  // 6250
    gat_final<<<dim3(fblocks), dim3(256), 0, stream>>>(out, cacc, Z);
}

// Round 2
// 169.573 us; speedup vs baseline: 1.7389x; 1.7389x over previous
//
#include <hip/hip_runtime.h>

#define NN 50000
#define EE 1600000
#define INF 128
#define OUTF 64
#define NH 2
#define ALPHA 0.2f

#define RNG 8            // node ranges (LDS privatization)
#define CHK 32           // edge chunks
#define NPR (NN / RNG)   // 6250 nodes per range
#define EPC (EE / CHK)   // 50000 edges per chunk

// ws layout (floats):
//   si      [0        , 100000)
//   sj      [100000   , 200000)
//   cf      [200000   , 300000)   normalized scale c[n,h]/Z[h]
//   Z       [300000   , 300002)
//   partial [300008   , 300008 + CHK*100000)   ~12.8 MB

__global__ __launch_bounds__(128)
void gat_node(const float* __restrict__ x, const float* __restrict__ W,
              const float* __restrict__ a, float* __restrict__ out,
              float* __restrict__ si, float* __restrict__ sj,
              float* __restrict__ Z)
{
    __shared__ float Wl[INF * OUTF];        // 32 KB: W[head][i][o] -> Wl[i*64+o]
    const int h = blockIdx.x & 1;
    const int n0 = (blockIdx.x >> 1) * 128;

    {
        const float4* src = (const float4*)(W + h * (INF * OUTF));
        float4* dst = (float4*)Wl;
        #pragma unroll 4
        for (int k = threadIdx.x; k < (INF * OUTF) / 4; k += 128) dst[k] = src[k];
    }
    if (blockIdx.x == 0 && threadIdx.x < 2) Z[threadIdx.x] = 0.0f;

    const int tx = threadIdx.x & 7;   // output octet
    const int ty = threadIdx.x >> 3;  // node group

    float ai[8], aj[8];
    #pragma unroll
    for (int c = 0; c < 8; ++c) {
        ai[c] = a[h * 2 * OUTF + tx * 8 + c];
        aj[c] = a[h * 2 * OUTF + OUTF + tx * 8 + c];
    }

    unsigned xoff[8];                 // byte offsets of the 8 node rows
    #pragma unroll
    for (int k = 0; k < 8; ++k) {
        int n = n0 + ty * 8 + k;
        if (n >= NN) n = NN - 1;      // clamp: loads valid, stores guarded
        xoff[k] = (unsigned)n * (INF * 4);
    }

    float acc[8][8];
    #pragma unroll
    for (int k = 0; k < 8; ++k)
        #pragma unroll
        for (int c = 0; c < 8; ++c) acc[k][c] = 0.0f;

    __syncthreads();

    const char* xc = (const char*)x;
    for (int i4 = 0; i4 < INF / 4; ++i4) {
        float4 xv[8];
        #pragma unroll
        for (int k = 0; k < 8; ++k)
            xv[k] = *(const float4*)(xc + xoff[k] + i4 * 16);

        float4 wa[4], wb[4];
        #pragma unroll
        for (int r = 0; r < 4; ++r) {
            const float* wrow = &Wl[(i4 * 4 + r) * OUTF + tx * 8];
            wa[r] = *(const float4*)(wrow);
            wb[r] = *(const float4*)(wrow + 4);
        }
        #pragma unroll
        for (int k = 0; k < 8; ++k) {
            const float* xk = (const float*)&xv[k];
            #pragma unroll
            for (int r = 0; r < 4; ++r) {
                const float xs = xk[r];
                acc[k][0] = fmaf(xs, wa[r].x, acc[k][0]);
                acc[k][1] = fmaf(xs, wa[r].y, acc[k][1]);
                acc[k][2] = fmaf(xs, wa[r].z, acc[k][2]);
                acc[k][3] = fmaf(xs, wa[r].w, acc[k][3]);
                acc[k][4] = fmaf(xs, wb[r].x, acc[k][4]);
                acc[k][5] = fmaf(xs, wb[r].y, acc[k][5]);
                acc[k][6] = fmaf(xs, wb[r].z, acc[k][6]);
                acc[k][7] = fmaf(xs, wb[r].w, acc[k][7]);
            }
        }
    }

    #pragma unroll
    for (int k = 0; k < 8; ++k) {
        float pi = 0.0f, pj = 0.0f;
        #pragma unroll
        for (int c = 0; c < 8; ++c) {
            pi = fmaf(acc[k][c], ai[c], pi);
            pj = fmaf(acc[k][c], aj[c], pj);
        }
        #pragma unroll
        for (int m = 1; m < 8; m <<= 1) {
            pi += __shfl_xor(pi, m, 64);
            pj += __shfl_xor(pj, m, 64);
        }
        const int n = n0 + ty * 8 + k;
        if (n < NN) {
            if (tx == 0) {
                si[2 * n + h] = pi;
                sj[2 * n + h] = pj;
            }
            float4* o4 = (float4*)(out + (size_t)n * (NH * OUTF) + h * OUTF + tx * 8);
            o4[0] = make_float4(acc[k][0], acc[k][1], acc[k][2], acc[k][3]);
            o4[1] = make_float4(acc[k][4], acc[k][5], acc[k][6], acc[k][7]);
        }
    }
}

// grid = RNG*CHK blocks; block (r,c) histograms chunk c's edges whose dst
// falls in range r, into LDS, then flushes (non-atomic) to partial[c].
__global__ __launch_bounds__(512)
void gat_hist(const int* __restrict__ ei, const float* __restrict__ si,
              const float* __restrict__ sj, float* __restrict__ partial,
              float* __restrict__ Z)
{
    __shared__ float bins[NPR * 2];   // 50 KB
    __shared__ float zr0[8], zr1[8];
    const int r = blockIdx.x / CHK;
    const int c = blockIdx.x % CHK;
    const int nlo = r * NPR;

    {
        float4* b4 = (float4*)bins;
        #pragma unroll 4
        for (int i = threadIdx.x; i < NPR * 2 / 4; i += 512)
            b4[i] = make_float4(0.f, 0.f, 0.f, 0.f);
    }
    __syncthreads();

    const int ebase = c * EPC;
    float z0 = 0.0f, z1 = 0.0f;

    for (int i = threadIdx.x; i < EPC / 4; i += 512) {
        const int4 s4 = *(const int4*)&ei[ebase + 4 * i];
        const int4 d4 = *(const int4*)&ei[EE + ebase + 4 * i];
        const int ss[4] = {s4.x, s4.y, s4.z, s4.w};
        const int dd[4] = {d4.x, d4.y, d4.z, d4.w};
        #pragma unroll
        for (int k = 0; k < 4; ++k) {
            const unsigned rel = (unsigned)(dd[k] - nlo);
            if (rel < NPR) {
                const float2 vi = *(const float2*)&si[2 * ss[k]];
                const float2 vj = *(const float2*)&sj[2 * dd[k]];
                float a0 = vi.x + vj.x; a0 = a0 > 0.0f ? a0 : ALPHA * a0;
                float a1 = vi.y + vj.y; a1 = a1 > 0.0f ? a1 : ALPHA * a1;
                const float w0 = expf(a0);
                const float w1 = expf(a1);
                atomicAdd(&bins[2 * rel], w0);
                atomicAdd(&bins[2 * rel + 1], w1);
                z0 += w0; z1 += w1;
            }
        }
    }

    #pragma unroll
    for (int m = 1; m < 64; m <<= 1) {
        z0 += __shfl_xor(z0, m, 64);
        z1 += __shfl_xor(z1, m, 64);
    }
    const int wv = threadIdx.x >> 6;
    if ((threadIdx.x & 63) == 0) { zr0[wv] = z0; zr1[wv] = z1; }
    __syncthreads();                      // also orders all LDS bin adds
    if (threadIdx.x == 0) {
        float t0 = 0.f, t1 = 0.f;
        #pragma unroll
        for (int i = 0; i < 8; ++i) { t0 += zr0[i]; t1 += zr1[i]; }
        atomicAdd(&Z[0], t0);
        atomicAdd(&Z[1], t1);
    }

    float* P = partial + (size_t)c * 100000 + nlo * 2;
    const float4* b4 = (const float4*)bins;
    #pragma unroll 4
    for (int i = threadIdx.x; i < NPR * 2 / 4; i += 512)
        ((float4*)P)[i] = b4[i];
}

__global__ __launch_bounds__(256)
void gat_sum(const float* __restrict__ partial, float* __restrict__ cf,
             const float* __restrict__ Z)
{
    const int i = blockIdx.x * 256 + threadIdx.x;   // float4 index, 25000 total
    if (i >= 100000 / 4) return;
    float4 s = make_float4(0.f, 0.f, 0.f, 0.f);
    #pragma unroll 8
    for (int c = 0; c < CHK; ++c) {
        const float4 v = ((const float4*)(partial + (size_t)c * 100000))[i];
        s.x += v.x; s.y += v.y; s.z += v.z; s.w += v.w;
    }
    const float r0 = 1.0f / Z[0], r1 = 1.0f / Z[1];
    s.x *= r0; s.y *= r1; s.z *= r0; s.w *= r1;     // bin index parity = head
    ((float4*)cf)[i] = s;
}

__global__ __launch_bounds__(256)
void gat_final(float* __restrict__ out, const float* __restrict__ cf)
{
    const int total4 = NN * NH * OUTF / 4;   // 1,600,000
    const int idx = blockIdx.x * 256 + threadIdx.x;
    if (idx >= total4) return;
    const int base = idx << 2;
    const int n = base >> 7;
    const int h = (base >> 6) & 1;
    const float scale = cf[2 * n + h];
    float4* p = (float4*)out + idx;
    float4 v = *p;
    v.x *= scale; v.y *= scale; v.z *= scale; v.w *= scale;
    *p = v;
}

extern "C" void kernel_launch(void* const* d_in, const int* in_sizes, int n_in,
                              void* d_out, int out_size, void* d_ws, size_t ws_size,
                              hipStream_t stream)
{
    const float* x = (const float*)d_in[0];
    const float* W = (const float*)d_in[1];
    const float* a = (const float*)d_in[2];
    const int* ei = (const int*)d_in[3];
    float* out = (float*)d_out;
    float* ws = (float*)d_ws;

    float* si = ws;
    float* sj = ws + 100000;
    float* cf = ws + 200000;
    float* Z = ws + 300000;
    float* partial = ws + 300008;

    const int tiles = (NN + 127) / 128;                    // 391
    gat_node<<<dim3(tiles * NH), dim3(128), 0, stream>>>(x, W, a, out, si, sj, Z);

    gat_hist<<<dim3(RNG * CHK), dim3(512), 0, stream>>>(ei, si, sj, partial, Z);

    gat_sum<<<dim3((100000 / 4 + 255) / 256), dim3(256), 0, stream>>>(partial, cf, Z);

    const int fblocks = (NN * NH * OUTF / 4 + 255) / 256;  // 6250
    gat_final<<<dim3(fblocks), dim3(256), 0, stream>>>(out, cf);
}